// Round 5
// baseline (385.090 us; speedup 1.0000x reference)
//
#include <hip/hip_runtime.h>

// conv3d(8ci->8co, 3x3x3, same) + relu/leaky/gelu/sigmoid + bias, via bf16 MFMA.
//
// GEMM view: D[m][n] = sum_k A[m][k] * B[k][n]
//   m = w-position (16 per MFMA tile), n = c_out (8 used of 16),
//   k = tap*8 + ci, tap = kd*9+kh*3+kw in [0,27), padded to 28 taps (K=224, 7 steps).
// LDS x-layout is [slice][h][w][ci] bf16 (ci innermost, 16 B per spatial point):
// one lane's A fragment (1 tap x 8 ci) = one ds_read_b128. Weights = B operand,
// preloaded to 28 VGPRs. 4-slot d-slice ring, one barrier per d iteration.
//
// R9 results (first clean bench): passed, absmax 0.0156, rocprof 117 us.
// Counters: MfmaUtil 9.8, VALUBusy 42.5, HBM 32% peak, bank-conflict 1.5%,
// Occupancy 37% with VGPR=44 -> GRID-limited (1024 blocks = 4/CU = 50% cap).
// No pipe saturated => latency/barrier-bound: stage loads (~600 cyc HBM) sit
// exposed before the per-iteration barrier, too few waves to hide them.
//
// R10: (1) d-split 2->4: ND=8, grid 2048, LDS 25.3KB -> 6 blocks/CU = 24
// waves/CU (75% cap). d-halo 10/8 slices (+11% fetch, fine at 32% BW); skip
// the stage on the last iteration (slice d0+ND+1 never read).
// (2) T14 issue-early/write-late: stage_load (global->regs) at iteration top,
// MFMA + act + stores in the middle, vmcnt-drain + pack + ds_write at the
// bottom -- load latency hides under compute. Point geometry (div/mod, bounds,
// LDS offsets) hoisted out of the d-loop (d-invariant).
// __launch_bounds__(256,6) to keep VGPR <= 85 for 6 waves/SIMD.

#define CIN 8
#define COUT 8
#define DDIM 32
#define HDIM 128
#define WDIM 128
#define HWSZ (HDIM * WDIM)           // 16384
#define CISTR (DDIM * HWSZ)          // x ci stride in floats

#define ROWPTS 66                    // w = -1..64 (64-wide tile + halo)
#define ROWB   (ROWPTS * 16)         // 1056 B
#define SROWS  6                     // h = -1..4 (4-high tile + halo)
#define SLICEPTS (SROWS * ROWPTS)    // 396 points
#define SLICEB (SROWS * ROWB)        // 6336 B
#define NSLOT 4
#define LDSB (NSLOT * SLICEB)        // 25344 B
#define ND 8                         // d-iterations per block (dsplit = 32/ND = 4)

typedef short short8 __attribute__((ext_vector_type(8)));
typedef float floatx4 __attribute__((ext_vector_type(4)));

static __device__ __forceinline__ unsigned f2bf(float f) {
    unsigned u = __builtin_bit_cast(unsigned, f);
    return (u + 0x7FFFu + ((u >> 16) & 1u)) >> 16;   // RTN-even bf16
}

static __device__ __forceinline__ float act(float v, float bco) {
    float y = fmaxf(v, 0.f);                         // relu (leaky is identity after relu)
    float t = 0.7978845608028654f * (y + 0.044715f * y * y * y);
    float e = __builtin_amdgcn_exp2f(2.8853900817779268f * t);       // e^{2t}
    float g = y - y * __builtin_amdgcn_rcpf(1.f + e);                // tanh-gelu
    float s = __builtin_amdgcn_rcpf(1.f + __builtin_amdgcn_exp2f(-1.4426950408889634f * g));
    return s + bco;                                  // sigmoid + channel bias
}

// Block: 256 threads = 4 waves; wave w handles output h-row (h0+w), 4 w-chunks of 16.
// Grid: 2 wb * 32 hb * 8 b * 4 dsplit = 2048 blocks; ND=8 d-iterations per block.
__global__ __launch_bounds__(256, 6) void conv3d_mfma_kernel(
    const float* __restrict__ x,
    const float* __restrict__ wgt,
    const float* __restrict__ bias,
    float* __restrict__ out)
{
    __shared__ __align__(16) char lds[LDSB];

    const int tid  = threadIdx.x;
    const int lane = tid & 63;
    const int wid  = tid >> 6;        // wave id = local h row 0..3
    const int m    = lane & 15;       // A-row (w pos) for A; n (c_out) for B and C/D
    const int g    = lane >> 4;       // k-group 0..3

    int bx = blockIdx.x;
    const int wb = bx & 1;   bx >>= 1;
    const int hb = bx & 31;  bx >>= 5;
    const int b  = bx & 7;   bx >>= 3;
    const int d0 = bx * ND;           // d split
    const int h0 = hb * 4;
    const int W0 = wb * 64;

    const float* xb = x + (size_t)b * CIN * CISTR;

    // ---- B fragments (weights), 7 k-steps, lane: n=m(lane&15), k-run tap=4t+g, ci=j ----
    short8 bw[7];
    #pragma unroll
    for (int t = 0; t < 7; ++t) {
        const int tap = 4 * t + g;
        #pragma unroll
        for (int j = 0; j < 8; ++j) {
            float v = (m < 8 && tap < 27) ? wgt[(m * CIN + j) * 27 + tap] : 0.f;
            bw[t][j] = (short)f2bf(v);
        }
    }
    const float bco = (m < 8) ? bias[m] : 0.f;

    // ---- per-lane A-address invariants ----
    // slice (d+kd-1) lives in slot ((d+kd-1)+1)&3 = (d+kd)&3  ->  kdo[t] = kd.
    // Pad tap 27: B=0, so read any ALWAYS-STAGED slot (kdo=0) -- never the
    // in-flight slot (d+3)&3 and never uninitialized LDS (NaN*0 = NaN!).
    int kdo[7], inv[7];
    #pragma unroll
    for (int t = 0; t < 7; ++t) {
        const int tap = 4 * t + g;    // 0..27 (27 = zero pad; B=0 so value irrelevant)
        const int kd = tap / 9, r = tap % 9;
        const int kh = r / 3, kw = r % 3;
        kdo[t] = (tap < 27) ? kd : 0;
        inv[t] = kh * ROWB + (m + kw) * 16 + wid * ROWB;
    }

    // ---- staging geometry, d-invariant: 2 points per thread (p = tid, tid+256) ----
    // okhw includes p<SLICEPTS; write-predicate is p<SLICEPTS alone (halo points
    // MUST be written as zeros).
    int  soff[2];
    bool okhw[2];
    int  ldso[2];
    #pragma unroll
    for (int i = 0; i < 2; ++i) {
        const int p  = tid + 256 * i;
        const int hh = p / ROWPTS, ww = p - hh * ROWPTS;
        const int hg = h0 + hh - 1, wg = W0 + ww - 1;
        okhw[i] = (p < SLICEPTS) & ((unsigned)hg < HDIM) & ((unsigned)wg < WDIM);
        soff[i] = hg * WDIM + wg;          // junk when !okhw -- never dereferenced
        ldso[i] = p * 16;
    }
    const bool wr1 = (tid + 256) < SLICEPTS;   // thread has a second point

    // ---- split staging: issue loads early, pack+write late (T14) ----
    auto stage_load = [&](int dg, float (&r)[2][8]) {
        const float* xs = xb + (size_t)dg * HWSZ;
        const bool din = (unsigned)dg < DDIM;
        #pragma unroll
        for (int i = 0; i < 2; ++i) {
            const bool ok = okhw[i] & din;
            const float* src = xs + soff[i];
            #pragma unroll
            for (int c = 0; c < 8; ++c)
                r[i][c] = ok ? src[c * CISTR] : 0.f;   // coalesced per-ci loads
        }
    };
    auto stage_write = [&](int dg, float (&r)[2][8]) {
        char* sb = lds + ((dg + 1) & 3) * SLICEB;      // slice dg -> slot (dg+1)&3
        #pragma unroll
        for (int i = 0; i < 2; ++i) {
            if (i == 1 && !wr1) break;
            unsigned q[4];
            #pragma unroll
            for (int c = 0; c < 4; ++c)
                q[c] = f2bf(r[i][2 * c]) | (f2bf(r[i][2 * c + 1]) << 16);
            *(int4*)(sb + ldso[i]) = make_int4(q[0], q[1], q[2], q[3]);  // consecutive b128: no conflict
        }
    };

    // ---- prologue: slices d0-1, d0, d0+1 ----
    {
        float r[2][8];
        stage_load(d0 - 1, r); stage_write(d0 - 1, r);
        stage_load(d0,     r); stage_write(d0,     r);
        stage_load(d0 + 1, r); stage_write(d0 + 1, r);
    }
    __syncthreads();

    for (int d = d0; d < d0 + ND; ++d) {
        // A: issue next-slice loads (slice d+2 -> slot (d+3)&3, disjoint from reads)
        float r[2][8];
        const bool do_stage = (d + 2 <= d0 + ND);      // last needed slice is d0+ND
        if (do_stage) stage_load(d + 2, r);

        // B: MFMA over slots (d..d+2)&3 -- independent of the in-flight loads
        floatx4 acc0 = {0,0,0,0}, acc1 = {0,0,0,0}, acc2 = {0,0,0,0}, acc3 = {0,0,0,0};
        #pragma unroll
        for (int t = 0; t < 7; ++t) {
            const char* ap = lds + ((d + kdo[t]) & 3) * SLICEB + inv[t];
            short8 a0 = __builtin_bit_cast(short8, *(const int4*)(ap      ));
            short8 a1 = __builtin_bit_cast(short8, *(const int4*)(ap + 256));
            short8 a2 = __builtin_bit_cast(short8, *(const int4*)(ap + 512));
            short8 a3 = __builtin_bit_cast(short8, *(const int4*)(ap + 768));
            acc0 = __builtin_amdgcn_mfma_f32_16x16x32_bf16(a0, bw[t], acc0, 0, 0, 0);
            acc1 = __builtin_amdgcn_mfma_f32_16x16x32_bf16(a1, bw[t], acc1, 0, 0, 0);
            acc2 = __builtin_amdgcn_mfma_f32_16x16x32_bf16(a2, bw[t], acc2, 0, 0, 0);
            acc3 = __builtin_amdgcn_mfma_f32_16x16x32_bf16(a3, bw[t], acc3, 0, 0, 0);
        }

        // C: epilogue. n = lane&15 (c_out), rows m = g*4+reg -> 4 consecutive w
        if (m < 8) {
            float* op = out + ((size_t)(b * COUT + m) * DDIM + d) * HWSZ
                            + (h0 + wid) * WDIM + W0 + g * 4;
            *(float4*)(op)      = make_float4(act(acc0[0],bco), act(acc0[1],bco), act(acc0[2],bco), act(acc0[3],bco));
            *(float4*)(op + 16) = make_float4(act(acc1[0],bco), act(acc1[1],bco), act(acc1[2],bco), act(acc1[3],bco));
            *(float4*)(op + 32) = make_float4(act(acc2[0],bco), act(acc2[1],bco), act(acc2[2],bco), act(acc2[3],bco));
            *(float4*)(op + 48) = make_float4(act(acc3[0],bco), act(acc3[1],bco), act(acc3[2],bco), act(acc3[3],bco));
        }

        // D: drain loads, pack, write LDS just before the barrier
        if (do_stage) stage_write(d + 2, r);
        __syncthreads();
    }
}

extern "C" void kernel_launch(void* const* d_in, const int* in_sizes, int n_in,
                              void* d_out, int out_size, void* d_ws, size_t ws_size,
                              hipStream_t stream) {
    const float* x    = (const float*)d_in[0];
    const float* wgt  = (const float*)d_in[1];
    const float* bias = (const float*)d_in[2];
    float* out = (float*)d_out;

    dim3 grid(2 * 32 * 8 * 4);   // wb * hb * b * dsplit = 2048
    dim3 block(256);
    conv3d_mfma_kernel<<<grid, block, 0, stream>>>(x, wgt, bias, out);
}

// Round 6
// 314.195 us; speedup vs baseline: 1.2256x; 1.2256x over previous
//
#include <hip/hip_runtime.h>

// conv3d(8ci->8co, 3x3x3, same) + relu/leaky/gelu/sigmoid + bias, via bf16 MFMA.
//
// GEMM view: D[m][n] = sum_k A[m][k] * B[k][n]
//   m = w-position (16 per MFMA tile), n = c_out (8 used of 16),
//   k = tap*8 + ci, tap = kd*9+kh*3+kw in [0,27), padded to 28 taps (K=224, 7 steps).
// LDS x-layout is [slice][h][w][ci] bf16 (ci innermost, 16 B per spatial point):
// one lane's A fragment (1 tap x 8 ci) = one ds_read_b128. Weights = B operand,
// preloaded to 28 VGPRs. 4-slot d-slice ring, one barrier per d iteration.
//
// R9 baseline (verified): 117 us, FETCH 160 MB, WRITE 131 MB, Mfma 9.8,
// VALU 42.5, Occ 37, HBM 32%.
// R10 post-mortem (d-split x4 + T14 together): 235 us. FETCH 295 MB (+84%!),
// WRITE 215 MB (+64%, epilogue unchanged => cache thrash, not request growth).
// Effective BW ~2.2 TB/s flat => time tracked traffic. Lesson: dispatch-pattern
// changes inflate traffic nonlinearly here; d-split reverted.
//
// R11: isolate T14 on the R9 config. Grid 1024 / ND=16 / bounds(256,4) exactly
// as R9; keep only (a) issue-early/write-late staging split with a
// sched_barrier(0) pin after load issue, (b) hoisted d-invariant staging
// geometry, (c) skip of the useless final stage (18->17 slices, -5.5% fetch).
// A/B readout: FETCH must return to ~150 MB / WRITE ~131 MB.

#define CIN 8
#define COUT 8
#define DDIM 32
#define HDIM 128
#define WDIM 128
#define HWSZ (HDIM * WDIM)           // 16384
#define CISTR (DDIM * HWSZ)          // x ci stride in floats

#define ROWPTS 66                    // w = -1..64 (64-wide tile + halo)
#define ROWB   (ROWPTS * 16)         // 1056 B
#define SROWS  6                     // h = -1..4 (4-high tile + halo)
#define SLICEPTS (SROWS * ROWPTS)    // 396 points
#define SLICEB (SROWS * ROWB)        // 6336 B
#define NSLOT 4
#define LDSB (NSLOT * SLICEB)        // 25344 B
#define ND 16                        // d-iterations per block (dsplit = 32/ND = 2)

typedef short short8 __attribute__((ext_vector_type(8)));
typedef float floatx4 __attribute__((ext_vector_type(4)));

static __device__ __forceinline__ unsigned f2bf(float f) {
    unsigned u = __builtin_bit_cast(unsigned, f);
    return (u + 0x7FFFu + ((u >> 16) & 1u)) >> 16;   // RTN-even bf16
}

static __device__ __forceinline__ float act(float v, float bco) {
    float y = fmaxf(v, 0.f);                         // relu (leaky is identity after relu)
    float t = 0.7978845608028654f * (y + 0.044715f * y * y * y);
    float e = __builtin_amdgcn_exp2f(2.8853900817779268f * t);       // e^{2t}
    float g = y - y * __builtin_amdgcn_rcpf(1.f + e);                // tanh-gelu
    float s = __builtin_amdgcn_rcpf(1.f + __builtin_amdgcn_exp2f(-1.4426950408889634f * g));
    return s + bco;                                  // sigmoid + channel bias
}

// Block: 256 threads = 4 waves; wave w handles output h-row (h0+w), 4 w-chunks of 16.
// Grid: 2 wb * 32 hb * 8 b * 2 dsplit = 1024 blocks; ND=16 d-iterations per block.
__global__ __launch_bounds__(256, 4) void conv3d_mfma_kernel(
    const float* __restrict__ x,
    const float* __restrict__ wgt,
    const float* __restrict__ bias,
    float* __restrict__ out)
{
    __shared__ __align__(16) char lds[LDSB];

    const int tid  = threadIdx.x;
    const int lane = tid & 63;
    const int wid  = tid >> 6;        // wave id = local h row 0..3
    const int m    = lane & 15;       // A-row (w pos) for A; n (c_out) for B and C/D
    const int g    = lane >> 4;       // k-group 0..3

    int bx = blockIdx.x;
    const int wb = bx & 1;   bx >>= 1;
    const int hb = bx & 31;  bx >>= 5;
    const int b  = bx & 7;   bx >>= 3;
    const int d0 = bx * ND;           // d split
    const int h0 = hb * 4;
    const int W0 = wb * 64;

    const float* xb = x + (size_t)b * CIN * CISTR;

    // ---- B fragments (weights), 7 k-steps, lane: n=m(lane&15), k-run tap=4t+g, ci=j ----
    short8 bw[7];
    #pragma unroll
    for (int t = 0; t < 7; ++t) {
        const int tap = 4 * t + g;
        #pragma unroll
        for (int j = 0; j < 8; ++j) {
            float v = (m < 8 && tap < 27) ? wgt[(m * CIN + j) * 27 + tap] : 0.f;
            bw[t][j] = (short)f2bf(v);
        }
    }
    const float bco = (m < 8) ? bias[m] : 0.f;

    // ---- per-lane A-address invariants ----
    // slice (d+kd-1) lives in slot ((d+kd-1)+1)&3 = (d+kd)&3  ->  kdo[t] = kd.
    // Pad tap 27: B=0, so read any ALWAYS-STAGED slot (kdo=0) -- never the
    // in-flight slot (d+3)&3 and never uninitialized LDS (NaN*0 = NaN!).
    int kdo[7], inv[7];
    #pragma unroll
    for (int t = 0; t < 7; ++t) {
        const int tap = 4 * t + g;    // 0..27 (27 = zero pad; B=0 so value irrelevant)
        const int kd = tap / 9, r = tap % 9;
        const int kh = r / 3, kw = r % 3;
        kdo[t] = (tap < 27) ? kd : 0;
        inv[t] = kh * ROWB + (m + kw) * 16 + wid * ROWB;
    }

    // ---- staging geometry, d-invariant: 2 points per thread (p = tid, tid+256) ----
    // okhw includes p<SLICEPTS; write-predicate is p<SLICEPTS alone (halo points
    // MUST be written as zeros).
    int  soff[2];
    bool okhw[2];
    int  ldso[2];
    #pragma unroll
    for (int i = 0; i < 2; ++i) {
        const int p  = tid + 256 * i;
        const int hh = p / ROWPTS, ww = p - hh * ROWPTS;
        const int hg = h0 + hh - 1, wg = W0 + ww - 1;
        okhw[i] = (p < SLICEPTS) & ((unsigned)hg < HDIM) & ((unsigned)wg < WDIM);
        soff[i] = hg * WDIM + wg;          // junk when !okhw -- never dereferenced
        ldso[i] = p * 16;
    }
    const bool wr1 = (tid + 256) < SLICEPTS;   // thread has a second point

    // ---- split staging: issue loads early, pack+write late (T14) ----
    auto stage_load = [&](int dg, float (&r)[2][8]) {
        const float* xs = xb + (size_t)dg * HWSZ;
        const bool din = (unsigned)dg < DDIM;
        #pragma unroll
        for (int i = 0; i < 2; ++i) {
            const bool ok = okhw[i] & din;
            const float* src = xs + soff[i];
            #pragma unroll
            for (int c = 0; c < 8; ++c)
                r[i][c] = ok ? src[c * CISTR] : 0.f;   // coalesced per-ci loads
        }
    };
    auto stage_write = [&](int dg, float (&r)[2][8]) {
        char* sb = lds + ((dg + 1) & 3) * SLICEB;      // slice dg -> slot (dg+1)&3
        #pragma unroll
        for (int i = 0; i < 2; ++i) {
            if (i == 1 && !wr1) break;
            unsigned q[4];
            #pragma unroll
            for (int c = 0; c < 4; ++c)
                q[c] = f2bf(r[i][2 * c]) | (f2bf(r[i][2 * c + 1]) << 16);
            *(int4*)(sb + ldso[i]) = make_int4(q[0], q[1], q[2], q[3]);  // consecutive b128: no conflict
        }
    };

    // ---- prologue: slices d0-1, d0, d0+1 ----
    {
        float r[2][8];
        stage_load(d0 - 1, r); stage_write(d0 - 1, r);
        stage_load(d0,     r); stage_write(d0,     r);
        stage_load(d0 + 1, r); stage_write(d0 + 1, r);
    }
    __syncthreads();

    for (int d = d0; d < d0 + ND; ++d) {
        // A: issue next-slice loads (slice d+2 -> slot (d+3)&3, disjoint from reads).
        // sched_barrier(0) pins the load issue here -- compiler must not sink
        // the loads down to their first use in stage_write.
        float r[2][8];
        const bool do_stage = (d + 2 <= d0 + ND);      // last needed slice is d0+ND
        if (do_stage) {
            stage_load(d + 2, r);
            __builtin_amdgcn_sched_barrier(0);
        }

        // B: MFMA over slots (d..d+2)&3 -- independent of the in-flight loads
        floatx4 acc0 = {0,0,0,0}, acc1 = {0,0,0,0}, acc2 = {0,0,0,0}, acc3 = {0,0,0,0};
        #pragma unroll
        for (int t = 0; t < 7; ++t) {
            const char* ap = lds + ((d + kdo[t]) & 3) * SLICEB + inv[t];
            short8 a0 = __builtin_bit_cast(short8, *(const int4*)(ap      ));
            short8 a1 = __builtin_bit_cast(short8, *(const int4*)(ap + 256));
            short8 a2 = __builtin_bit_cast(short8, *(const int4*)(ap + 512));
            short8 a3 = __builtin_bit_cast(short8, *(const int4*)(ap + 768));
            acc0 = __builtin_amdgcn_mfma_f32_16x16x32_bf16(a0, bw[t], acc0, 0, 0, 0);
            acc1 = __builtin_amdgcn_mfma_f32_16x16x32_bf16(a1, bw[t], acc1, 0, 0, 0);
            acc2 = __builtin_amdgcn_mfma_f32_16x16x32_bf16(a2, bw[t], acc2, 0, 0, 0);
            acc3 = __builtin_amdgcn_mfma_f32_16x16x32_bf16(a3, bw[t], acc3, 0, 0, 0);
        }

        // C: epilogue. n = lane&15 (c_out), rows m = g*4+reg -> 4 consecutive w
        if (m < 8) {
            float* op = out + ((size_t)(b * COUT + m) * DDIM + d) * HWSZ
                            + (h0 + wid) * WDIM + W0 + g * 4;
            *(float4*)(op)      = make_float4(act(acc0[0],bco), act(acc0[1],bco), act(acc0[2],bco), act(acc0[3],bco));
            *(float4*)(op + 16) = make_float4(act(acc1[0],bco), act(acc1[1],bco), act(acc1[2],bco), act(acc1[3],bco));
            *(float4*)(op + 32) = make_float4(act(acc2[0],bco), act(acc2[1],bco), act(acc2[2],bco), act(acc2[3],bco));
            *(float4*)(op + 48) = make_float4(act(acc3[0],bco), act(acc3[1],bco), act(acc3[2],bco), act(acc3[3],bco));
        }

        // D: drain loads, pack, write LDS just before the barrier
        if (do_stage) stage_write(d + 2, r);
        __syncthreads();
    }
}

extern "C" void kernel_launch(void* const* d_in, const int* in_sizes, int n_in,
                              void* d_out, int out_size, void* d_ws, size_t ws_size,
                              hipStream_t stream) {
    const float* x    = (const float*)d_in[0];
    const float* wgt  = (const float*)d_in[1];
    const float* bias = (const float*)d_in[2];
    float* out = (float*)d_out;

    dim3 grid(2 * 32 * 8 * 2);   // wb * hb * b * dsplit = 1024
    dim3 block(256);
    conv3d_mfma_kernel<<<grid, block, 0, stream>>>(x, wgt, bias, out);
}

// Round 7
// 280.919 us; speedup vs baseline: 1.3708x; 1.1185x over previous
//
#include <hip/hip_runtime.h>

// conv3d(8ci->8co, 3x3x3, same) + relu/leaky/gelu/sigmoid + bias, via bf16 MFMA.
//
// GEMM view, DUAL-D: D[m][n] = sum_k A[m][k] * B[k][n]
//   m = w-position (16 per tile), n = co + 8*s  (s in {0,1} = output slice d+s)
//   k = tap'*8 + ci, tap' = kd'*9 + kh*3 + kw, kd' in [0,4) over slices d-1..d+2.
//   B[tap'][co+8s] = (kd'-s in [0,3)) ? w[co][ci][kd'-s,kh,kw] : 0.
//   36 taps = 9 k-steps of K=32, NO pad tap. One MFMA tile computes two output
//   d-slices -> all 16 N-cols useful: act() epilogue 100% lane-useful (was 50%),
//   36 MFMAs + 36 ds_reads per 2 outputs (was 56), 1 barrier per 2 outputs.
// LDS x-layout [slice][h][w][ci] bf16, 6-slot ring (slices d-1..d+4 live),
// slice s -> slot (s+1) mod 6; per iteration stage slices d+3, d+4.
//
// History: R9 = 117 us verified baseline (FETCH 160 MB, WRITE 131, Mfma 9.8,
// VALU 42.5, Occ 37, HBM 32% -- no pipe saturated, VALU largest).
// R10 (d-split x4 + T14): 235 us, FETCH +84% -- dispatch-pattern cache thrash.
// R11 (T14 isolated on R9 config): traffic clean (155/131 MB) but 155 us,
// VALU and Mfma both DROPPED -> explicit load-pin (sched_barrier) defeats the
// compiler's own overlap; T14 reverted for good (Common-mistake #5).
// R12 (this): dual-d N-packing. Act was the biggest VALU/trans sink at 50%
// lane-waste; this removes the waste structurally instead of rescheduling.

#define CIN 8
#define COUT 8
#define DDIM 32
#define HDIM 128
#define WDIM 128
#define HWSZ (HDIM * WDIM)           // 16384
#define CISTR (DDIM * HWSZ)          // x ci stride in floats

#define ROWPTS 66                    // w = -1..64 (64-wide tile + halo)
#define ROWB   (ROWPTS * 16)         // 1056 B
#define SROWS  6                     // h = -1..4 (4-high tile + halo)
#define SLICEPTS (SROWS * ROWPTS)    // 396 points
#define SLICEB (SROWS * ROWB)        // 6336 B
#define NSLOT 6
#define LDSB (NSLOT * SLICEB)        // 38016 B -> 4 blocks/CU (152 KB of 160)
#define ND 16                        // output d per block (dsplit = 2); step 2

typedef short short8 __attribute__((ext_vector_type(8)));
typedef float floatx4 __attribute__((ext_vector_type(4)));

static __device__ __forceinline__ unsigned f2bf(float f) {
    unsigned u = __builtin_bit_cast(unsigned, f);
    return (u + 0x7FFFu + ((u >> 16) & 1u)) >> 16;   // RTN-even bf16
}

static __device__ __forceinline__ float act(float v, float bco) {
    float y = fmaxf(v, 0.f);                         // relu (leaky is identity after relu)
    float t = 0.7978845608028654f * (y + 0.044715f * y * y * y);
    float e = __builtin_amdgcn_exp2f(2.8853900817779268f * t);       // e^{2t}
    float g = y - y * __builtin_amdgcn_rcpf(1.f + e);                // tanh-gelu
    float s = __builtin_amdgcn_rcpf(1.f + __builtin_amdgcn_exp2f(-1.4426950408889634f * g));
    return s + bco;                                  // sigmoid + channel bias
}

// Block: 256 threads = 4 waves; wave w handles output h-row (h0+w), 4 w-chunks of 16.
// Grid: 2 wb * 32 hb * 8 b * 2 dsplit = 1024 blocks; 8 dual-d iterations per block.
__global__ __launch_bounds__(256, 4) void conv3d_mfma_kernel(
    const float* __restrict__ x,
    const float* __restrict__ wgt,
    const float* __restrict__ bias,
    float* __restrict__ out)
{
    __shared__ __align__(16) char lds[LDSB];

    const int tid  = threadIdx.x;
    const int lane = tid & 63;
    const int wid  = tid >> 6;        // wave id = local h row 0..3
    const int m    = lane & 15;       // A-row (w pos); also n = co + 8*s for B, C/D
    const int g    = lane >> 4;       // k-group 0..3
    const int co   = m & 7;           // output channel  (B/C/D cols)
    const int ds   = m >> 3;          // output d offset s in {0,1}

    int bx = blockIdx.x;
    const int wb = bx & 1;   bx >>= 1;
    const int hb = bx & 31;  bx >>= 5;
    const int b  = bx & 7;   bx >>= 3;
    const int d0 = bx * ND;           // d split: d0 in {0,16}
    const int h0 = hb * 4;
    const int W0 = wb * 64;

    const float* xb = x + (size_t)b * CIN * CISTR;

    // ---- B fragments (weights), 9 k-steps over 36 taps', n = co+8*ds ----
    // tap' = 4t+g; kd' = tap'/9; contribution to out[d+ds] exists iff
    // kd'-ds in [0,3), with weight tap (kd'-ds)*9 + kh*3 + kw.
    short8 bw[9];
    unsigned aoff[9];                 // per-lane A byte offset: kd'*SLICEB + spatial
    #pragma unroll
    for (int t = 0; t < 9; ++t) {
        const int tap = 4 * t + g;    // 0..35, no pad
        const int kd = tap / 9, r = tap % 9;
        const int kh = r / 3, kw = r % 3;
        const int kds = kd - ds;
        const bool wok = (kds >= 0) & (kds < 3);
        #pragma unroll
        for (int j = 0; j < 8; ++j) {
            float v = wok ? wgt[(co * CIN + j) * 27 + kds * 9 + kh * 3 + kw] : 0.f;
            bw[t][j] = (short)f2bf(v);
        }
        aoff[t] = (unsigned)(kd * SLICEB + (kh + wid) * ROWB + (m + kw) * 16);
    }
    const float bco = bias[co];

    // ---- staging geometry, d-invariant: 2 points per thread (p = tid, tid+256) ----
    int  soff[2];
    bool okhw[2];
    int  ldso[2];
    #pragma unroll
    for (int i = 0; i < 2; ++i) {
        const int p  = tid + 256 * i;
        const int hh = p / ROWPTS, ww = p - hh * ROWPTS;
        const int hg = h0 + hh - 1, wg = W0 + ww - 1;
        okhw[i] = (p < SLICEPTS) & ((unsigned)hg < HDIM) & ((unsigned)wg < WDIM);
        soff[i] = hg * WDIM + wg;          // junk when !okhw -- never dereferenced
        ldso[i] = p * 16;
    }

    // ---- staging: slice dg -> slot (dg+1)%6, zero-fill outside the volume ----
    // Fused load+pack+write (R9 style): compiler overlaps it with MFMAs itself.
    auto stage = [&](int dg) {
        char* sb = lds + ((dg + 1) % NSLOT) * SLICEB;
        const float* xs = xb + (size_t)dg * HWSZ;
        const bool din = (unsigned)dg < DDIM;
        #pragma unroll
        for (int i = 0; i < 2; ++i) {
            const int p = tid + 256 * i;
            if (p < SLICEPTS) {
                const bool ok = okhw[i] & din;
                const float* src = xs + soff[i];
                unsigned q[4];
                #pragma unroll
                for (int c = 0; c < 4; ++c) {
                    float v0 = ok ? src[(2 * c    ) * CISTR] : 0.f;   // coalesced per-ci loads
                    float v1 = ok ? src[(2 * c + 1) * CISTR] : 0.f;
                    q[c] = f2bf(v0) | (f2bf(v1) << 16);
                }
                *(int4*)(sb + ldso[i]) = make_int4(q[0], q[1], q[2], q[3]);
            }
        }
    };

    // ---- prologue: slices d0-1 .. d0+2 ----
    stage(d0 - 1); stage(d0); stage(d0 + 1); stage(d0 + 2);
    __syncthreads();

    // slot of slice s is (s+1)%6; A-read for iter d, kd' is slice d-1+kd'
    // -> slot (d+kd')%6. Maintain sdB = (d%6)*SLICEB incrementally; per-tap
    // wrap is one compare+select on the byte offset (no runtime div).
    unsigned sdB = (unsigned)(d0 % NSLOT) * SLICEB;

    for (int d = d0; d < d0 + ND; d += 2) {
        // stage slices d+3, d+4 -> slots (d+4)%6,(d+5)%6; reads use (d..d+3)%6.
        // Last needed slice is d0+ND; both conds reduce to d+4 <= d0+ND.
        if (d + 4 <= d0 + ND) { stage(d + 3); stage(d + 4); }

        floatx4 acc0 = {0,0,0,0}, acc1 = {0,0,0,0}, acc2 = {0,0,0,0}, acc3 = {0,0,0,0};
        #pragma unroll
        for (int t = 0; t < 9; ++t) {
            unsigned off = sdB + aoff[t];
            off = (off >= (unsigned)LDSB) ? off - (unsigned)LDSB : off;
            const char* ap = lds + off;
            short8 a0 = __builtin_bit_cast(short8, *(const int4*)(ap      ));
            short8 a1 = __builtin_bit_cast(short8, *(const int4*)(ap + 256));
            short8 a2 = __builtin_bit_cast(short8, *(const int4*)(ap + 512));
            short8 a3 = __builtin_bit_cast(short8, *(const int4*)(ap + 768));
            acc0 = __builtin_amdgcn_mfma_f32_16x16x32_bf16(a0, bw[t], acc0, 0, 0, 0);
            acc1 = __builtin_amdgcn_mfma_f32_16x16x32_bf16(a1, bw[t], acc1, 0, 0, 0);
            acc2 = __builtin_amdgcn_mfma_f32_16x16x32_bf16(a2, bw[t], acc2, 0, 0, 0);
            acc3 = __builtin_amdgcn_mfma_f32_16x16x32_bf16(a3, bw[t], acc3, 0, 0, 0);
        }

        // C/D: col n = co+8*ds, rows = g*4+reg -> 4 consecutive w. ALL 64 lanes
        // store (act fully useful). Per (co,ds): 4 g-lanes fill a 64B line.
        {
            float* op = out + ((size_t)(b * COUT + co) * DDIM + (d + ds)) * HWSZ
                            + (h0 + wid) * WDIM + W0 + g * 4;
            *(float4*)(op)      = make_float4(act(acc0[0],bco), act(acc0[1],bco), act(acc0[2],bco), act(acc0[3],bco));
            *(float4*)(op + 16) = make_float4(act(acc1[0],bco), act(acc1[1],bco), act(acc1[2],bco), act(acc1[3],bco));
            *(float4*)(op + 32) = make_float4(act(acc2[0],bco), act(acc2[1],bco), act(acc2[2],bco), act(acc2[3],bco));
            *(float4*)(op + 48) = make_float4(act(acc3[0],bco), act(acc3[1],bco), act(acc3[2],bco), act(acc3[3],bco));
        }

        __syncthreads();
        sdB += 2 * SLICEB;
        if (sdB >= (unsigned)LDSB) sdB -= (unsigned)LDSB;
    }
}

extern "C" void kernel_launch(void* const* d_in, const int* in_sizes, int n_in,
                              void* d_out, int out_size, void* d_ws, size_t ws_size,
                              hipStream_t stream) {
    const float* x    = (const float*)d_in[0];
    const float* wgt  = (const float*)d_in[1];
    const float* bias = (const float*)d_in[2];
    float* out = (float*)d_out;

    dim3 grid(2 * 32 * 8 * 2);   // wb * hb * b * dsplit = 1024
    dim3 block(256);
    conv3d_mfma_kernel<<<grid, block, 0, stream>>>(x, wgt, bias, out);
}